// Round 1
// 128.149 us; speedup vs baseline: 1.0085x; 1.0085x over previous
//
#include <hip/hip_runtime.h>

// Degenerate-reference algebra (verified R2/R4/R5/R6, absmax <= 0.0625):
//   out[b,t,n] = sum_d V_sum[b,d] * WoH[d,n] + bo[n]      (constant over t)
//   V_sum[b,:] = (sum_t x[b,t,:]) @ Wv + T*bv
//   WoH[d,n]   = sum_h Wo[64h+d, n]
//
// R8 theory: dur_us (129.2) ~= 3.07x the harness's 256 MiB ws-poison fills
// (42 us each @ 80% HBM peak, top-5 of rocprof) -> large fixed component.
// Our kernels are ~15-20 us of it (traffic floor: x 32.8 MB read + out
// 32.8 MB write + Wo 4.2 MB = ~11 us). This round removes the last real
// waste: stage2 recomputed row[b,n] (only 32 KB of unique data!) in all
// 512 blocks (128 MB L2 Wv traffic + 16 MB partial re-reads + serialized
// A-C ahead of every store block). Split: rowcalc (32 blocks, once) +
// bcast (1000 blocks, pure streaming float4 stores at write BW).
// Prediction: dur 123-126 if kernel time is additive; unchanged 128-130
// => floor is harness-imposed => ROOFLINE.

namespace {
constexpr int B    = 8;
constexpr int T    = 1000;
constexpr int D    = 1024;
constexpr int HD   = 64;
constexpr int NSEG = 8;      // t-segments of 125 rows
constexpr int TSZ  = 125;
}

// ---------------------------------------------------------------------------
// K1 (320 blocks) — unchanged from R7:
//  blocks 0..255  : (seg, b, qc) -> partial[(seg*B+b)*D + qc*256 .. +255]
//                   = sum_{t in seg} x[b,t,qc-slice]; 4 row-groups x 64
//                   float4-lanes, LDS reduce, one 1 KB write per block.
//  blocks 256..319: WoH[d*D+n] = sum_h Wo[(h*HD+d)*D+n]  (4 entries/thread)
// ---------------------------------------------------------------------------
__global__ __launch_bounds__(256)
void stage1_kernel(const float* __restrict__ x, const float* __restrict__ Wo,
                   float* __restrict__ partial, float* __restrict__ WoH)
{
    const int blk = blockIdx.x;
    const int t   = threadIdx.x;
    if (blk < 256) {
        __shared__ float4 red[4][64];
        const int seg = blk & 7;
        const int b   = (blk >> 3) & 7;
        const int qc  = blk >> 6;                  // 0..3
        const int rg  = t >> 6;                    // row group 0..3
        const int cl  = t & 63;                    // float4 lane
        const int t0  = seg * TSZ;
        float4 acc = make_float4(0.f, 0.f, 0.f, 0.f);
        const float* base = x + ((size_t)b * T + t0) * D + qc * 256 + cl * 4;
        for (int r = rg; r < TSZ; r += 4) {        // 31-32 iters, 1 KB/wave/iter
            const float4 v = *(const float4*)(base + (size_t)r * D);
            acc.x += v.x; acc.y += v.y; acc.z += v.z; acc.w += v.w;
        }
        red[rg][cl] = acc;
        __syncthreads();
        if (t < 64) {
            const float4 a0 = red[0][t], a1 = red[1][t];
            const float4 a2 = red[2][t], a3 = red[3][t];
            const float4 s = make_float4(a0.x + a1.x + a2.x + a3.x,
                                         a0.y + a1.y + a2.y + a3.y,
                                         a0.z + a1.z + a2.z + a3.z,
                                         a0.w + a1.w + a2.w + a3.w);
            *(float4*)(partial + ((size_t)(seg * B + b)) * D + qc * 256 + t * 4) = s;
        }
    } else {
        const int gtid = (blk - 256) * 256 + t;    // 0..16383
        #pragma unroll
        for (int e = 0; e < 4; ++e) {
            const int idx = e * 16384 + gtid;      // 0..65535 == HD*D
            const int d = idx >> 10, n = idx & 1023;
            float w = 0.f;
            #pragma unroll
            for (int h = 0; h < 16; ++h)
                w += Wo[(size_t)(h * HD + d) * D + n];   // coalesced over n
            WoH[idx] = w;
        }
    }
}

// ---------------------------------------------------------------------------
// K2a rowcalc (grid 4 x 8 = 32 blocks): per block (nq, b), ONCE:
//   A: xs[1024] = sum_{s<8} partial[(s*B+b)*D + .]   (8-deep float4, L2-hot)
//   B: vs[d] = xs . Wv[:,d] + T*bv[d]                (split-4 over c,
//                                                     4-acc unroll: 1 wave/SIMD
//                                                     here, break fmaf chain)
//   C: row[b*D + nq*256 + t] = vs . WoH[:,n] + bo[n] (64-deep, coalesced)
// Unique row data is only 8*1024 floats = 32 KB; R7 recomputed it 16x.
// ---------------------------------------------------------------------------
__global__ __launch_bounds__(256)
void rowcalc_kernel(const float* __restrict__ partial, const float* __restrict__ Wv,
                    const float* __restrict__ bv, const float* __restrict__ WoH,
                    const float* __restrict__ bo, float* __restrict__ row)
{
    __shared__ float xs_l[D];
    __shared__ float prt[4][HD];
    __shared__ float vs_l[HD];
    const int nq = blockIdx.x;         // 0..3
    const int b  = blockIdx.y;         // 0..7
    const int t  = threadIdx.x;

    // --- A ---
    {
        const int c4 = t * 4;
        float4 acc = make_float4(0.f, 0.f, 0.f, 0.f);
        const float* p = partial + (size_t)b * D + c4;
        #pragma unroll
        for (int s = 0; s < NSEG; ++s) {
            const float4 v = *(const float4*)(p + (size_t)s * (B * D));
            acc.x += v.x; acc.y += v.y; acc.z += v.z; acc.w += v.w;
        }
        *(float4*)&xs_l[c4] = acc;
    }
    __syncthreads();

    // --- B ---
    {
        const int d = t & 63, qr = t >> 6;
        const int c0 = qr * 256;
        float a0 = 0.f, a1 = 0.f, a2 = 0.f, a3 = 0.f;
        for (int i = 0; i < 256; i += 4) {
            a0 = fmaf(xs_l[c0 + i + 0], Wv[(size_t)(c0 + i + 0) * HD + d], a0);
            a1 = fmaf(xs_l[c0 + i + 1], Wv[(size_t)(c0 + i + 1) * HD + d], a1);
            a2 = fmaf(xs_l[c0 + i + 2], Wv[(size_t)(c0 + i + 2) * HD + d], a2);
            a3 = fmaf(xs_l[c0 + i + 3], Wv[(size_t)(c0 + i + 3) * HD + d], a3);
        }
        prt[qr][d] = (a0 + a1) + (a2 + a3);
    }
    __syncthreads();
    if (t < HD)
        vs_l[t] = prt[0][t] + prt[1][t] + prt[2][t] + prt[3][t]
                + (float)T * bv[t];
    __syncthreads();

    // --- C ---
    {
        const int n = nq * 256 + t;
        float acc = bo[n];
        #pragma unroll
        for (int d = 0; d < HD; ++d)
            acc = fmaf(vs_l[d], WoH[d * D + n], acc);
        row[(size_t)b * D + n] = acc;
    }
}

// ---------------------------------------------------------------------------
// K2b bcast (grid 8 x 125 = 1000 blocks): per block (b, tc):
//   load row[b, t*4..t*4+3] (4 KB/block, L2-hot: unique data 32 KB total),
//   stream 8 output rows of coalesced float4 stores (32 KB/block).
// Pure write-BW kernel: 32.8 MB total ~ 5.3 us at 6.3 TB/s.
// ---------------------------------------------------------------------------
__global__ __launch_bounds__(256)
void bcast_kernel(const float* __restrict__ row, float* __restrict__ out)
{
    const int b  = blockIdx.x;         // 0..7
    const int tc = blockIdx.y;         // 0..124
    const int t  = threadIdx.x;
    const float4 val = *(const float4*)(row + (size_t)b * D + t * 4);
    float* obase = out + ((size_t)b * T + (size_t)tc * 8) * D + t * 4;
    #pragma unroll
    for (int r = 0; r < 8; ++r)
        *(float4*)(obase + (size_t)r * D) = val;
}

// ---------------------------------------------------------------------------
extern "C" void kernel_launch(void* const* d_in, const int* in_sizes, int n_in,
                              void* d_out, int out_size, void* d_ws, size_t ws_size,
                              hipStream_t stream)
{
    const float* x  = (const float*)d_in[0];
    const float* Wv = (const float*)d_in[5];
    const float* bv = (const float*)d_in[6];
    const float* Wo = (const float*)d_in[7];
    const float* bo = (const float*)d_in[8];
    float* out = (float*)d_out;

    // ws layout (floats): partial[8*8*1024] (256 KB) | WoH[64*1024] (256 KB)
    //                     | row[8*1024] (32 KB)
    float* partial = (float*)d_ws;
    float* WoH = partial + (size_t)NSEG * B * D;
    float* row = WoH + (size_t)HD * D;

    stage1_kernel <<<dim3(320),      256, 0, stream>>>(x, Wo, partial, WoH);
    rowcalc_kernel<<<dim3(4, B),     256, 0, stream>>>(partial, Wv, bv, WoH,
                                                       bo, row);
    bcast_kernel  <<<dim3(B, 125),   256, 0, stream>>>(row, out);
}